// Round 6
// baseline (973.253 us; speedup 1.0000x reference)
//
#include <hip/hip_runtime.h>
#include <hip/hip_bf16.h>

#define D_   256
#define K_   1024
#define HW_  1024
#define B_   64
#define N_   65536

#define OFF_ZQ   ((size_t)0)
#define OFF_LOSS ((size_t)16777216)
#define OFF_IDX  ((size_t)16777217)
#define OFF_PERP ((size_t)16842753)
#define OFF_USED ((size_t)16842754)
#define OFF_ENEW ((size_t)16843778)
#define OFF_CSN  ((size_t)17105922)
#define OFF_EAVG ((size_t)17106946)

#define DECAY_F 0.99f
#define W_NEW   ((float)(1.0 - 0.99))
#define EPS_F   1e-5f
#define KEPS_F  ((float)(1024.0 * 1e-5))
#define MARGIN  0.00390625f

// ws layout (float offsets)
#define WS_E2      0        // 1024
#define WS_CNT     1024     // 1024
#define WS_LOSS    2048     // 1
#define WS_FLAGCNT 2052     // 1 (int)
#define WS_SMOO    2304     // 1024
#define WS_OFFS    3328     // 1024 (int)
#define WS_CURS    4352     // 1024 (int)
#define WS_Z2      8192     // 65536
#define WS_BUCKET  73728    // 65536 (int)
#define WS_FLAG    139264   // 65536 (int)

typedef __attribute__((ext_vector_type(8))) short bf16x8;
typedef __attribute__((ext_vector_type(8))) unsigned short u16x8;
typedef __attribute__((ext_vector_type(4))) float f32x4;

static __device__ __forceinline__ float bf2f(unsigned short u) {
    return __uint_as_float(((unsigned int)u) << 16);
}
static __device__ __forceinline__ unsigned short f2bf(float x) {
    unsigned int u = __float_as_uint(x);
    return (unsigned short)((u + 0x7fffu + ((u >> 16) & 1u)) >> 16);
}

// ---------------- prep_z: z[b][d][hw] f32 -> zhiT/zloT [pt][d] bf16 + z2 ----
__global__ __launch_bounds__(256) void prep_z(
    const float* __restrict__ z, unsigned short* __restrict__ zhi,
    unsigned short* __restrict__ zlo, float* __restrict__ z2g) {
    __shared__ float tile[128][68];
    __shared__ double zred[64][4];
    const int tid = threadIdx.x;
    const int b   = blockIdx.x >> 4;
    const int hw0 = (blockIdx.x & 15) * 64;
    const float* zb = z + (size_t)b * (D_ * HW_);

    const int hw = tid >> 2, dq = tid & 3;
    double zacc = 0.0;

    for (int h = 0; h < 2; ++h) {
        #pragma unroll
        for (int ch = 0; ch < 8; ++ch) {
            int d = h * 128 + ch * 16 + (tid >> 4);
            int c4 = (tid & 15) * 4;
            float4 v = *(const float4*)&zb[(size_t)d * HW_ + hw0 + c4];
            tile[ch * 16 + (tid >> 4)][c4 + 0] = v.x;
            tile[ch * 16 + (tid >> 4)][c4 + 1] = v.y;
            tile[ch * 16 + (tid >> 4)][c4 + 2] = v.z;
            tile[ch * 16 + (tid >> 4)][c4 + 3] = v.w;
        }
        __syncthreads();
        size_t pt = (size_t)b * HW_ + hw0 + hw;
        #pragma unroll
        for (int jb = 0; jb < 4; ++jb) {
            unsigned short hs[8], ls[8];
            #pragma unroll
            for (int e = 0; e < 8; ++e) {
                float v = tile[dq * 32 + jb * 8 + e][hw];
                zacc += (double)v * (double)v;
                unsigned short hh = f2bf(v);
                hs[e] = hh;
                ls[e] = f2bf(v - bf2f(hh));
            }
            size_t dst = pt * D_ + h * 128 + dq * 32 + jb * 8;
            *(u16x8*)&zhi[dst] = *(u16x8*)hs;
            *(u16x8*)&zlo[dst] = *(u16x8*)ls;
        }
        __syncthreads();
    }
    zred[hw][dq] = zacc;
    __syncthreads();
    if (tid < 64) {
        double s = zred[tid][0] + zred[tid][1] + zred[tid][2] + zred[tid][3];
        z2g[b * HW_ + hw0 + tid] = (float)s;
    }
}

// ---------------- prep_e: E[k][d] f32 -> ehi/elo bf16 + e2 (f64) ------------
__global__ __launch_bounds__(64) void prep_e(
    const float* __restrict__ E, unsigned short* __restrict__ ehi,
    unsigned short* __restrict__ elo, float* __restrict__ e2g) {
    int k = blockIdx.x;
    int lane = threadIdx.x;
    float4 v = *(const float4*)&E[(size_t)k * D_ + lane * 4];
    double s = (double)v.x * v.x + (double)v.y * v.y +
               (double)v.z * v.z + (double)v.w * v.w;
    float vv[4] = {v.x, v.y, v.z, v.w};
    ushort4 hs, ls;
    unsigned short* hp = (unsigned short*)&hs;
    unsigned short* lp = (unsigned short*)&ls;
    #pragma unroll
    for (int e = 0; e < 4; ++e) {
        unsigned short hh = f2bf(vv[e]);
        hp[e] = hh;
        lp[e] = f2bf(vv[e] - bf2f(hh));
    }
    *(ushort4*)&ehi[(size_t)k * D_ + lane * 4] = hs;
    *(ushort4*)&elo[(size_t)k * D_ + lane * 4] = ls;
    #pragma unroll
    for (int m = 32; m > 0; m >>= 1) s += __shfl_xor(s, m, 64);
    if (lane == 0) e2g[k] = (float)s;
}

// ---------------- argmin via bf16x3 MFMA: 128 pts/block, 512 thr, 1/CU ------
// LDS: 2 planes x 128 pts x 256 d shorts = 128 KB, swizzled. 8 waves =
// 2 pt-halves x 4 code-quarters. Each wave: 64 pts x 256 codes via
// ks-loop (4 x 64-code chunks) x dc-loop (8 x 32-d). No main-loop barriers.
__global__ __launch_bounds__(512, 1) void argmin_mfma(
    const unsigned short* __restrict__ zhi, const unsigned short* __restrict__ zlo,
    const unsigned short* __restrict__ ehi, const unsigned short* __restrict__ elo,
    const float* __restrict__ e2g, float* __restrict__ out_idx,
    int* __restrict__ flagged, int* __restrict__ flagcnt) {
    __shared__ unsigned short zl[2][128][256];             // 128 KB
    float (*mred)[64][3] = (float(*)[64][3])&zl[0][0][0];  // aliased post-loop

    const int tid  = threadIdx.x;
    const int lane = tid & 63;
    const int wid  = tid >> 6;
    const int wr = wid >> 2, wc = wid & 3;   // pt-half, code-quarter
    const int x = lane & 15, g = lane >> 4;
    const int pt0 = blockIdx.x * 128;

    // ---- stage both z planes once (coalesced 16B chunks, swizzled dest)
    {
        #pragma unroll
        for (int i = 0; i < 16; ++i) {
            int c = i * 512 + tid;          // 16B chunk id, 0..8191
            int plane = c >> 12;
            int r = c & 4095;
            int pt = r >> 5, d16 = r & 31;
            int soff = (d16 * 8) ^ ((pt & 7) << 3);
            const unsigned short* src = (plane ? zlo : zhi) + (size_t)(pt0 + pt) * D_ + d16 * 8;
            *(u16x8*)&zl[plane][pt][soff] = *(const u16x8*)src;
        }
    }
    __syncthreads();

    float m1[16], m2[16];
    int   a1[16];
    #pragma unroll
    for (int s = 0; s < 16; ++s) { m1[s] = 3.4e38f; m2[s] = 3.4e38f; a1[s] = 0; }

    for (int ks = 0; ks < 4; ++ks) {
        f32x4 acc[4][4];
        #pragma unroll
        for (int mf = 0; mf < 4; ++mf)
            #pragma unroll
            for (int nf = 0; nf < 4; ++nf) acc[mf][nf] = (f32x4)0.f;

        for (int dc = 0; dc < 8; ++dc) {
            bf16x8 ah[4], al[4];
            #pragma unroll
            for (int mf = 0; mf < 4; ++mf) {
                int pt = wr * 64 + mf * 16 + x;
                int soff = (dc * 32 + g * 8) ^ ((pt & 7) << 3);
                ah[mf] = *(const bf16x8*)&zl[0][pt][soff];
                al[mf] = *(const bf16x8*)&zl[1][pt][soff];
            }
            bf16x8 bh[4], bl[4];
            #pragma unroll
            for (int nf = 0; nf < 4; ++nf) {
                int code = wc * 256 + ks * 64 + nf * 16 + x;
                size_t base = (size_t)code * D_ + dc * 32 + g * 8;
                bh[nf] = *(const bf16x8*)&ehi[base];
                bl[nf] = *(const bf16x8*)&elo[base];
            }
            #pragma unroll
            for (int mf = 0; mf < 4; ++mf)
                #pragma unroll
                for (int nf = 0; nf < 4; ++nf) {
                    acc[mf][nf] = __builtin_amdgcn_mfma_f32_16x16x32_bf16(ah[mf], bh[nf], acc[mf][nf], 0, 0, 0);
                    acc[mf][nf] = __builtin_amdgcn_mfma_f32_16x16x32_bf16(ah[mf], bl[nf], acc[mf][nf], 0, 0, 0);
                    acc[mf][nf] = __builtin_amdgcn_mfma_f32_16x16x32_bf16(al[mf], bh[nf], acc[mf][nf], 0, 0, 0);
                }
        }

        // epilogue: dist = e2 - 2S ; running (m1, a1, m2) per owned pt-slot
        float e2v[4];
        int   cbase[4];
        #pragma unroll
        for (int nf = 0; nf < 4; ++nf) {
            cbase[nf] = wc * 256 + ks * 64 + nf * 16 + x;
            e2v[nf] = e2g[cbase[nf]];
        }
        #pragma unroll
        for (int mf = 0; mf < 4; ++mf)
            #pragma unroll
            for (int reg = 0; reg < 4; ++reg) {
                int s = mf * 4 + reg;
                #pragma unroll
                for (int nf = 0; nf < 4; ++nf) {
                    float dist = __builtin_fmaf(-2.0f, acc[mf][nf][reg], e2v[nf]);
                    if (dist < m1[s]) { m2[s] = m1[s]; m1[s] = dist; a1[s] = cbase[nf]; }
                    else m2[s] = fminf(m2[s], dist);
                }
            }
    }

    // butterfly across the 16 col-lanes (x) sharing each pt (register-only)
    #pragma unroll
    for (int mask = 1; mask < 16; mask <<= 1) {
        #pragma unroll
        for (int s = 0; s < 16; ++s) {
            float om1 = __shfl_xor(m1[s], mask, 64);
            int   oa  = __shfl_xor(a1[s], mask, 64);
            float om2 = __shfl_xor(m2[s], mask, 64);
            bool take = (om1 < m1[s]) || (om1 == m1[s] && oa < a1[s]);
            float loser = take ? m1[s] : om1;
            m2[s] = fminf(fminf(m2[s], om2), loser);
            if (take) { m1[s] = om1; a1[s] = oa; }
        }
    }
    __syncthreads();   // all waves done reading zl before aliasing as mred
    if (x < 4) {
        #pragma unroll
        for (int reg = 0; reg < 4; ++reg) {
            int s = x * 4 + reg;
            int ptl = x * 16 + g * 4 + reg;   // pt within this wave's 64-half
            mred[wid][ptl][0] = m1[s];
            mred[wid][ptl][1] = (float)a1[s];
            mred[wid][ptl][2] = m2[s];
        }
    }
    __syncthreads();
    if (tid < 128) {
        int half = tid >> 6, ptl = tid & 63;
        int w0 = half * 4;
        float m1f = mred[w0][ptl][0], m2f = mred[w0][ptl][2];
        int   a1f = (int)mred[w0][ptl][1];
        #pragma unroll
        for (int w = 1; w < 4; ++w) {
            float om1 = mred[w0 + w][ptl][0], om2 = mred[w0 + w][ptl][2];
            int   oa  = (int)mred[w0 + w][ptl][1];
            bool take = (om1 < m1f) || (om1 == m1f && oa < a1f);
            float loser = take ? m1f : om1;
            m2f = fminf(fminf(m2f, om2), loser);
            if (take) { m1f = om1; a1f = oa; }
        }
        out_idx[pt0 + tid] = (float)a1f;
        if (m2f - m1f < MARGIN) {
            int pos = atomicAdd(flagcnt, 1);
            flagged[pos] = pt0 + tid;
        }
    }
}

// ---------------- rescue: exact f32 re-argmin for flagged points ------------
__global__ __launch_bounds__(256) void rescue_kernel(
    const float* __restrict__ z, const float* __restrict__ E,
    const float* __restrict__ e2g, const float* __restrict__ z2g,
    const int* __restrict__ flagged, const int* __restrict__ flagcnt,
    float* __restrict__ out_idx) {
    __shared__ float zs[8][257];
    __shared__ float zz[8];
    __shared__ float redm[256];
    __shared__ int   reda[256];
    const int tid = threadIdx.x;
    const int nflag = flagcnt[0];
    const int nb = (nflag + 7) >> 3;

    for (int bi = blockIdx.x; bi < nb; bi += gridDim.x) {
        int base = bi * 8;
        int cnt = nflag - base; if (cnt > 8) cnt = 8;
        for (int j = 0; j < cnt; ++j) {
            int p = flagged[base + j];
            zs[j][tid] = z[(size_t)(p >> 10) * (D_ * HW_) + (size_t)tid * HW_ + (p & 1023)];
        }
        if (tid < cnt) zz[tid] = z2g[flagged[base + tid]];
        __syncthreads();

        float mj[8], distc[8];
        int   aj[8];
        #pragma unroll
        for (int j = 0; j < 8; ++j) { mj[j] = 3.4e38f; aj[j] = 0; }

        for (int c = 0; c < 4; ++c) {
            int code = tid * 4 + c;
            const float* er = E + (size_t)code * D_;
            float accj[8];
            #pragma unroll
            for (int j = 0; j < 8; ++j) accj[j] = 0.f;
            for (int d = 0; d < D_; ++d) {
                float ev = er[d];
                #pragma unroll
                for (int j = 0; j < 8; ++j)
                    accj[j] = __builtin_fmaf(ev, zs[j][d], accj[j]);
            }
            float e2c = e2g[code];
            #pragma unroll
            for (int j = 0; j < 8; ++j) {
                distc[j] = __fsub_rn(__fadd_rn(zz[j], e2c), __fmul_rn(2.0f, accj[j]));
                if (distc[j] < mj[j]) { mj[j] = distc[j]; aj[j] = code; }
            }
        }
        for (int j = 0; j < cnt; ++j) {
            redm[tid] = mj[j]; reda[tid] = aj[j];
            __syncthreads();
            for (int s = 128; s > 0; s >>= 1) {
                if (tid < s) {
                    float om = redm[tid + s]; int oa = reda[tid + s];
                    if (om < redm[tid] || (om == redm[tid] && oa < reda[tid])) {
                        redm[tid] = om; reda[tid] = oa;
                    }
                }
                __syncthreads();
            }
            if (tid == 0) out_idx[flagged[base + j]] = (float)reda[0];
            __syncthreads();
        }
        __syncthreads();
    }
}

// ---------------- counts from final indices ---------------------------------
__global__ __launch_bounds__(256) void count_kernel(
    const float* __restrict__ idxf, float* __restrict__ counts) {
    int n = blockIdx.x * 256 + threadIdx.x;
    unsafeAtomicAdd(&counts[(int)idxf[n]], 1.0f);
}

// ---------------- quantize + zq + loss --------------------------------------
__global__ __launch_bounds__(256) void quant_kernel(
    const float* __restrict__ z, const float* __restrict__ E,
    const float* __restrict__ idxf, float* __restrict__ zq,
    float* __restrict__ lossacc) {
    const int b  = blockIdx.x >> 4;
    const int d0 = (blockIdx.x & 15) * 16;
    const int tid = threadIdx.x;
    const int hw = tid * 4;
    const float* zb = z  + (size_t)b * (D_ * HW_);
    float*       qb = zq + (size_t)b * (D_ * HW_);

    int idx[4];
    #pragma unroll
    for (int i = 0; i < 4; ++i) idx[i] = (int)idxf[b * HW_ + hw + i];

    float loss = 0.f;
    for (int db = 0; db < 4; ++db) {
        int d = d0 + db * 4;
        float qa[4][4];
        #pragma unroll
        for (int i = 0; i < 4; ++i)
            *(float4*)&qa[i][0] = *(const float4*)&E[(size_t)idx[i] * D_ + d];
        #pragma unroll
        for (int dd = 0; dd < 4; ++dd) {
            float4 z4 = *(const float4*)&zb[(size_t)(d + dd) * HW_ + hw];
            float zv[4] = {z4.x, z4.y, z4.z, z4.w};
            float o[4];
            #pragma unroll
            for (int i = 0; i < 4; ++i) {
                float diff = __fsub_rn(qa[i][dd], zv[i]);
                float zqv  = __fadd_rn(zv[i], diff);
                o[i] = zqv;
                float l = __fsub_rn(zqv, zv[i]);
                loss = __builtin_fmaf(l, l, loss);
            }
            *(float4*)&qb[(size_t)(d + dd) * HW_ + hw] = make_float4(o[0], o[1], o[2], o[3]);
        }
    }
    __shared__ float ls[256];
    ls[tid] = loss;
    __syncthreads();
    for (int s = 128; s > 0; s >>= 1) {
        if (tid < s) ls[tid] += ls[tid + s];
        __syncthreads();
    }
    if (tid == 0) unsafeAtomicAdd(lossacc, ls[0]);
}

// ---------------- per-code scalars ------------------------------------------
__global__ __launch_bounds__(1024) void fin1(
    const float* __restrict__ counts, const float* __restrict__ cs_in,
    float* __restrict__ out, float* __restrict__ smoothed) {
    const int k = threadIdx.x;
    __shared__ float red[1024];
    float c = counts[k];
    float csn = __fadd_rn(__fmul_rn(DECAY_F, cs_in[k]), __fmul_rn(W_NEW, c));
    out[OFF_CSN + k]  = csn;
    out[OFF_USED + k] = (c > 0.f) ? 1.f : 0.f;
    red[k] = csn; __syncthreads();
    for (int s = 512; s > 0; s >>= 1) { if (k < s) red[k] += red[k + s]; __syncthreads(); }
    float n_ = red[0]; __syncthreads();
    red[k] = c; __syncthreads();
    for (int s = 512; s > 0; s >>= 1) { if (k < s) red[k] += red[k + s]; __syncthreads(); }
    float total = red[0]; __syncthreads();
    float p = c / total;
    red[k] = p * logf(p + 1e-10f); __syncthreads();
    for (int s = 512; s > 0; s >>= 1) { if (k < s) red[k] += red[k + s]; __syncthreads(); }
    if (k == 0) out[OFF_PERP] = expf(-red[0]);
    smoothed[k] = __fmul_rn(__fdiv_rn(__fadd_rn(csn, EPS_F), __fadd_rn(n_, KEPS_F)), n_);
}

__global__ void fin_loss(const float* __restrict__ lossacc, float* __restrict__ out) {
    if (threadIdx.x == 0) out[OFF_LOSS] = lossacc[0] / 16777216.0f;
}

// ---------------- scan / scatter --------------------------------------------
__global__ __launch_bounds__(1024) void scan_kernel(
    const float* __restrict__ counts, int* __restrict__ offs,
    int* __restrict__ cursor) {
    __shared__ int s[1024];
    const int k = threadIdx.x;
    int c = (int)counts[k];
    s[k] = c; __syncthreads();
    for (int dlt = 1; dlt < 1024; dlt <<= 1) {
        int v = (k >= dlt) ? s[k - dlt] : 0;
        __syncthreads();
        s[k] += v;
        __syncthreads();
    }
    int off = s[k] - c;
    offs[k] = off;
    cursor[k] = off;
}

__global__ __launch_bounds__(256) void scatter_kernel(
    const float* __restrict__ idxf, int* __restrict__ cursor,
    int* __restrict__ bucket) {
    int n = blockIdx.x * 256 + threadIdx.x;
    int k = (int)idxf[n];
    int pos = atomicAdd(&cursor[k], 1);
    bucket[pos] = n;
}

// ---------------- per-code gather-sum (coalesced via bf16 planes) -----------
__global__ __launch_bounds__(256) void code_update(
    const unsigned short* __restrict__ zhi, const unsigned short* __restrict__ zlo,
    const float* __restrict__ eavg_in, const float* __restrict__ smoothed,
    const float* __restrict__ counts, const int* __restrict__ offs,
    const int* __restrict__ bucket, float* __restrict__ out) {
    const int k = blockIdx.x;
    const int d = threadIdx.x;
    const int off = offs[k];
    const int cnt = (int)counts[k];
    float acc = 0.f;
    for (int i = 0; i < cnt; ++i) {
        int p = bucket[off + i];
        size_t base = (size_t)p * D_ + d;
        acc += bf2f(zhi[base]) + bf2f(zlo[base]);
    }
    int e = k * D_ + d;
    float ean = __fadd_rn(__fmul_rn(DECAY_F, eavg_in[e]), __fmul_rn(W_NEW, acc));
    out[OFF_EAVG + e] = ean;
    out[OFF_ENEW + e] = __fdiv_rn(ean, smoothed[k]);
}

extern "C" void kernel_launch(void* const* d_in, const int* in_sizes, int n_in,
                              void* d_out, int out_size, void* d_ws, size_t ws_size,
                              hipStream_t stream) {
    const float* z    = (const float*)d_in[0];
    const float* E    = (const float*)d_in[1];
    const float* cs   = (const float*)d_in[2];
    const float* eavg = (const float*)d_in[3];
    float* out = (float*)d_out;
    float* wsf = (float*)d_ws;
    int*   wsi = (int*)d_ws;

    unsigned short* zhiP = (unsigned short*)(out + OFF_ZQ);
    unsigned short* zloP = zhiP + (size_t)N_ * D_;
    unsigned short* ehiP = (unsigned short*)(out + OFF_ENEW);
    unsigned short* eloP = ehiP + (size_t)K_ * D_;

    hipMemsetAsync(d_ws, 0, 32768, stream);  // counts, loss, flagcnt

    prep_z<<<1024, 256, 0, stream>>>(z, zhiP, zloP, wsf + WS_Z2);
    prep_e<<<K_, 64, 0, stream>>>(E, ehiP, eloP, wsf + WS_E2);
    argmin_mfma<<<N_ / 128, 512, 0, stream>>>(zhiP, zloP, ehiP, eloP,
                                              wsf + WS_E2, out + OFF_IDX,
                                              wsi + WS_FLAG, wsi + WS_FLAGCNT);
    rescue_kernel<<<256, 256, 0, stream>>>(z, E, wsf + WS_E2, wsf + WS_Z2,
                                           wsi + WS_FLAG, wsi + WS_FLAGCNT,
                                           out + OFF_IDX);
    count_kernel<<<N_ / 256, 256, 0, stream>>>(out + OFF_IDX, wsf + WS_CNT);
    fin1<<<1, 1024, 0, stream>>>(wsf + WS_CNT, cs, out, wsf + WS_SMOO);
    scan_kernel<<<1, 1024, 0, stream>>>(wsf + WS_CNT, wsi + WS_OFFS, wsi + WS_CURS);
    scatter_kernel<<<N_ / 256, 256, 0, stream>>>(out + OFF_IDX, wsi + WS_CURS,
                                                 wsi + WS_BUCKET);
    // code_update MUST precede quant_kernel: it reads the bf16 z-planes that
    // live in the OFF_ZQ output region, which quant_kernel overwrites.
    code_update<<<K_, 256, 0, stream>>>(zhiP, zloP, eavg, wsf + WS_SMOO,
                                        wsf + WS_CNT, wsi + WS_OFFS,
                                        wsi + WS_BUCKET, out);
    quant_kernel<<<B_ * 16, 256, 0, stream>>>(z, E, out + OFF_IDX, out + OFF_ZQ,
                                              wsf + WS_LOSS);
    fin_loss<<<1, 64, 0, stream>>>(wsf + WS_LOSS, out);
}

// Round 7
// 718.011 us; speedup vs baseline: 1.3555x; 1.3555x over previous
//
#include <hip/hip_runtime.h>
#include <hip/hip_bf16.h>

#define D_   256
#define K_   1024
#define HW_  1024
#define B_   64
#define N_   65536

#define OFF_ZQ   ((size_t)0)
#define OFF_LOSS ((size_t)16777216)
#define OFF_IDX  ((size_t)16777217)
#define OFF_PERP ((size_t)16842753)
#define OFF_USED ((size_t)16842754)
#define OFF_ENEW ((size_t)16843778)
#define OFF_CSN  ((size_t)17105922)
#define OFF_EAVG ((size_t)17106946)

#define DECAY_F 0.99f
#define W_NEW   ((float)(1.0 - 0.99))
#define EPS_F   1e-5f
#define KEPS_F  ((float)(1024.0 * 1e-5))
#define MARGIN  0.00390625f

// ws layout (float offsets)
#define WS_E2      0        // 1024
#define WS_CNT     1024     // 1024
#define WS_LOSS    2048     // 1
#define WS_FLAGCNT 2052     // 1 (int)
#define WS_SMOO    2304     // 1024
#define WS_OFFS    3328     // 1024 (int)
#define WS_CURS    4352     // 1024 (int)
#define WS_Z2      8192     // 65536
#define WS_BUCKET  73728    // 65536 (int)
#define WS_FLAG    139264   // 65536 (int)

typedef __attribute__((ext_vector_type(8))) short bf16x8;
typedef __attribute__((ext_vector_type(8))) unsigned short u16x8;
typedef __attribute__((ext_vector_type(4))) float f32x4;

static __device__ __forceinline__ float bf2f(unsigned short u) {
    return __uint_as_float(((unsigned int)u) << 16);
}
static __device__ __forceinline__ unsigned short f2bf(float x) {
    unsigned int u = __float_as_uint(x);
    return (unsigned short)((u + 0x7fffu + ((u >> 16) & 1u)) >> 16);
}

// ---------------- prep_z: z[b][d][hw] f32 -> zhiT/zloT [pt][d] bf16 + z2 ----
__global__ __launch_bounds__(256) void prep_z(
    const float* __restrict__ z, unsigned short* __restrict__ zhi,
    unsigned short* __restrict__ zlo, float* __restrict__ z2g) {
    __shared__ float tile[128][68];
    __shared__ double zred[64][4];
    const int tid = threadIdx.x;
    const int b   = blockIdx.x >> 4;
    const int hw0 = (blockIdx.x & 15) * 64;
    const float* zb = z + (size_t)b * (D_ * HW_);

    const int hw = tid >> 2, dq = tid & 3;
    double zacc = 0.0;

    for (int h = 0; h < 2; ++h) {
        #pragma unroll
        for (int ch = 0; ch < 8; ++ch) {
            int d = h * 128 + ch * 16 + (tid >> 4);
            int c4 = (tid & 15) * 4;
            float4 v = *(const float4*)&zb[(size_t)d * HW_ + hw0 + c4];
            tile[ch * 16 + (tid >> 4)][c4 + 0] = v.x;
            tile[ch * 16 + (tid >> 4)][c4 + 1] = v.y;
            tile[ch * 16 + (tid >> 4)][c4 + 2] = v.z;
            tile[ch * 16 + (tid >> 4)][c4 + 3] = v.w;
        }
        __syncthreads();
        size_t pt = (size_t)b * HW_ + hw0 + hw;
        #pragma unroll
        for (int jb = 0; jb < 4; ++jb) {
            unsigned short hs[8], ls[8];
            #pragma unroll
            for (int e = 0; e < 8; ++e) {
                float v = tile[dq * 32 + jb * 8 + e][hw];
                zacc += (double)v * (double)v;
                unsigned short hh = f2bf(v);
                hs[e] = hh;
                ls[e] = f2bf(v - bf2f(hh));
            }
            size_t dst = pt * D_ + h * 128 + dq * 32 + jb * 8;
            *(u16x8*)&zhi[dst] = *(u16x8*)hs;
            *(u16x8*)&zlo[dst] = *(u16x8*)ls;
        }
        __syncthreads();
    }
    zred[hw][dq] = zacc;
    __syncthreads();
    if (tid < 64) {
        double s = zred[tid][0] + zred[tid][1] + zred[tid][2] + zred[tid][3];
        z2g[b * HW_ + hw0 + tid] = (float)s;
    }
}

// ---------------- prep_e: E[k][d] f32 -> ehi/elo bf16 + e2 (f64) ------------
__global__ __launch_bounds__(64) void prep_e(
    const float* __restrict__ E, unsigned short* __restrict__ ehi,
    unsigned short* __restrict__ elo, float* __restrict__ e2g) {
    int k = blockIdx.x;
    int lane = threadIdx.x;
    float4 v = *(const float4*)&E[(size_t)k * D_ + lane * 4];
    double s = (double)v.x * v.x + (double)v.y * v.y +
               (double)v.z * v.z + (double)v.w * v.w;
    float vv[4] = {v.x, v.y, v.z, v.w};
    ushort4 hs, ls;
    unsigned short* hp = (unsigned short*)&hs;
    unsigned short* lp = (unsigned short*)&ls;
    #pragma unroll
    for (int e = 0; e < 4; ++e) {
        unsigned short hh = f2bf(vv[e]);
        hp[e] = hh;
        lp[e] = f2bf(vv[e] - bf2f(hh));
    }
    *(ushort4*)&ehi[(size_t)k * D_ + lane * 4] = hs;
    *(ushort4*)&elo[(size_t)k * D_ + lane * 4] = ls;
    #pragma unroll
    for (int m = 32; m > 0; m >>= 1) s += __shfl_xor(s, m, 64);
    if (lane == 0) e2g[k] = (float)s;
}

// ---------------- argmin via bf16x3 MFMA: 64 pts/block, 256 thr -------------
// PLAIN __launch_bounds__(256): no min-waves clamp -> full register budget,
// no scratch spill (r4/r6's 0.5 GB WRITE_SIZE came from the clamped budget).
// LDS: zl[2][64][256] shorts = 64 KB, XOR-swizzled; z staged ONCE; no
// main-loop barriers; 4 waves each own a 64-code slice per kt, kt=4.
__global__ __launch_bounds__(256) void argmin_mfma(
    const unsigned short* __restrict__ zhi, const unsigned short* __restrict__ zlo,
    const unsigned short* __restrict__ ehi, const unsigned short* __restrict__ elo,
    const float* __restrict__ e2g, float* __restrict__ out_idx,
    int* __restrict__ flagged, int* __restrict__ flagcnt) {
    __shared__ unsigned short zl[2][64][256];              // 64 KB exactly
    float (*mred)[64][3] = (float(*)[64][3])&zl[0][0][0];  // aliased post-loop

    const int tid  = threadIdx.x;
    const int lane = tid & 63;
    const int wid  = tid >> 6;
    const int x = lane & 15, g = lane >> 4;
    const int pt0 = blockIdx.x * 64;

    // ---- stage both z planes once (coalesced 16B chunks, swizzled dest)
    {
        const unsigned short* s0 = zhi + (size_t)pt0 * D_;
        const unsigned short* s1 = zlo + (size_t)pt0 * D_;
        #pragma unroll
        for (int i = 0; i < 8; ++i) {
            int c = i * 256 + tid;             // 16B chunk id, 0..2047
            int pt = c >> 5, d16 = c & 31;
            int soff = (d16 * 8) ^ ((pt & 7) << 3);
            *(u16x8*)&zl[0][pt][soff] = *(const u16x8*)&s0[c * 8];
            *(u16x8*)&zl[1][pt][soff] = *(const u16x8*)&s1[c * 8];
        }
    }
    __syncthreads();

    float m1[16], m2[16];
    int   a1[16];
    #pragma unroll
    for (int s = 0; s < 16; ++s) { m1[s] = 3.4e38f; m2[s] = 3.4e38f; a1[s] = 0; }

    for (int kt = 0; kt < 4; ++kt) {
        f32x4 acc[4][4];
        #pragma unroll
        for (int mf = 0; mf < 4; ++mf)
            #pragma unroll
            for (int nf = 0; nf < 4; ++nf) acc[mf][nf] = (f32x4)0.f;

        for (int dc = 0; dc < 8; ++dc) {
            bf16x8 ah[4], al[4];
            #pragma unroll
            for (int mf = 0; mf < 4; ++mf) {
                int pt = mf * 16 + x;
                int soff = (dc * 32 + g * 8) ^ ((pt & 7) << 3);
                ah[mf] = *(const bf16x8*)&zl[0][pt][soff];
                al[mf] = *(const bf16x8*)&zl[1][pt][soff];
            }
            bf16x8 bh[4], bl[4];
            #pragma unroll
            for (int nf = 0; nf < 4; ++nf) {
                int code = kt * 256 + wid * 64 + nf * 16 + x;
                size_t base = (size_t)code * D_ + dc * 32 + g * 8;
                bh[nf] = *(const bf16x8*)&ehi[base];
                bl[nf] = *(const bf16x8*)&elo[base];
            }
            #pragma unroll
            for (int mf = 0; mf < 4; ++mf)
                #pragma unroll
                for (int nf = 0; nf < 4; ++nf) {
                    acc[mf][nf] = __builtin_amdgcn_mfma_f32_16x16x32_bf16(ah[mf], bh[nf], acc[mf][nf], 0, 0, 0);
                    acc[mf][nf] = __builtin_amdgcn_mfma_f32_16x16x32_bf16(ah[mf], bl[nf], acc[mf][nf], 0, 0, 0);
                    acc[mf][nf] = __builtin_amdgcn_mfma_f32_16x16x32_bf16(al[mf], bh[nf], acc[mf][nf], 0, 0, 0);
                }
        }

        // epilogue: dist = e2 - 2S ; running (m1, a1, m2) per owned pt-slot
        float e2v[4];
        int   cbase[4];
        #pragma unroll
        for (int nf = 0; nf < 4; ++nf) {
            cbase[nf] = kt * 256 + wid * 64 + nf * 16 + x;
            e2v[nf] = e2g[cbase[nf]];
        }
        #pragma unroll
        for (int mf = 0; mf < 4; ++mf)
            #pragma unroll
            for (int reg = 0; reg < 4; ++reg) {
                int s = mf * 4 + reg;
                #pragma unroll
                for (int nf = 0; nf < 4; ++nf) {
                    float dist = __builtin_fmaf(-2.0f, acc[mf][nf][reg], e2v[nf]);
                    if (dist < m1[s]) { m2[s] = m1[s]; m1[s] = dist; a1[s] = cbase[nf]; }
                    else m2[s] = fminf(m2[s], dist);
                }
            }
    }

    // butterfly across the 16 col-lanes (x) sharing each pt (register-only)
    #pragma unroll
    for (int mask = 1; mask < 16; mask <<= 1) {
        #pragma unroll
        for (int s = 0; s < 16; ++s) {
            float om1 = __shfl_xor(m1[s], mask, 64);
            int   oa  = __shfl_xor(a1[s], mask, 64);
            float om2 = __shfl_xor(m2[s], mask, 64);
            bool take = (om1 < m1[s]) || (om1 == m1[s] && oa < a1[s]);
            float loser = take ? m1[s] : om1;
            m2[s] = fminf(fminf(m2[s], om2), loser);
            if (take) { m1[s] = om1; a1[s] = oa; }
        }
    }
    __syncthreads();   // all waves done reading zl before aliasing as mred
    if (x < 4) {
        #pragma unroll
        for (int reg = 0; reg < 4; ++reg) {
            int s = x * 4 + reg;
            int ptl = x * 16 + g * 4 + reg;
            mred[wid][ptl][0] = m1[s];
            mred[wid][ptl][1] = (float)a1[s];
            mred[wid][ptl][2] = m2[s];
        }
    }
    __syncthreads();
    if (tid < 64) {
        float m1f = mred[0][tid][0], m2f = mred[0][tid][2];
        int   a1f = (int)mred[0][tid][1];
        #pragma unroll
        for (int w = 1; w < 4; ++w) {
            float om1 = mred[w][tid][0], om2 = mred[w][tid][2];
            int   oa  = (int)mred[w][tid][1];
            bool take = (om1 < m1f) || (om1 == m1f && oa < a1f);
            float loser = take ? m1f : om1;
            m2f = fminf(fminf(m2f, om2), loser);
            if (take) { m1f = om1; a1f = oa; }
        }
        out_idx[pt0 + tid] = (float)a1f;
        if (m2f - m1f < MARGIN) {
            int pos = atomicAdd(flagcnt, 1);
            flagged[pos] = pt0 + tid;
        }
    }
}

// ---------------- rescue: exact f32 re-argmin for flagged points ------------
__global__ __launch_bounds__(256) void rescue_kernel(
    const float* __restrict__ z, const float* __restrict__ E,
    const float* __restrict__ e2g, const float* __restrict__ z2g,
    const int* __restrict__ flagged, const int* __restrict__ flagcnt,
    float* __restrict__ out_idx) {
    __shared__ float zs[8][257];
    __shared__ float zz[8];
    __shared__ float redm[256];
    __shared__ int   reda[256];
    const int tid = threadIdx.x;
    const int nflag = flagcnt[0];
    const int nb = (nflag + 7) >> 3;

    for (int bi = blockIdx.x; bi < nb; bi += gridDim.x) {
        int base = bi * 8;
        int cnt = nflag - base; if (cnt > 8) cnt = 8;
        for (int j = 0; j < cnt; ++j) {
            int p = flagged[base + j];
            zs[j][tid] = z[(size_t)(p >> 10) * (D_ * HW_) + (size_t)tid * HW_ + (p & 1023)];
        }
        if (tid < cnt) zz[tid] = z2g[flagged[base + tid]];
        __syncthreads();

        float mj[8], distc[8];
        int   aj[8];
        #pragma unroll
        for (int j = 0; j < 8; ++j) { mj[j] = 3.4e38f; aj[j] = 0; }

        for (int c = 0; c < 4; ++c) {
            int code = tid * 4 + c;
            const float* er = E + (size_t)code * D_;
            float accj[8];
            #pragma unroll
            for (int j = 0; j < 8; ++j) accj[j] = 0.f;
            for (int d = 0; d < D_; ++d) {
                float ev = er[d];
                #pragma unroll
                for (int j = 0; j < 8; ++j)
                    accj[j] = __builtin_fmaf(ev, zs[j][d], accj[j]);
            }
            float e2c = e2g[code];
            #pragma unroll
            for (int j = 0; j < 8; ++j) {
                distc[j] = __fsub_rn(__fadd_rn(zz[j], e2c), __fmul_rn(2.0f, accj[j]));
                if (distc[j] < mj[j]) { mj[j] = distc[j]; aj[j] = code; }
            }
        }
        for (int j = 0; j < cnt; ++j) {
            redm[tid] = mj[j]; reda[tid] = aj[j];
            __syncthreads();
            for (int s = 128; s > 0; s >>= 1) {
                if (tid < s) {
                    float om = redm[tid + s]; int oa = reda[tid + s];
                    if (om < redm[tid] || (om == redm[tid] && oa < reda[tid])) {
                        redm[tid] = om; reda[tid] = oa;
                    }
                }
                __syncthreads();
            }
            if (tid == 0) out_idx[flagged[base + j]] = (float)reda[0];
            __syncthreads();
        }
        __syncthreads();
    }
}

// ---------------- counts from final indices ---------------------------------
__global__ __launch_bounds__(256) void count_kernel(
    const float* __restrict__ idxf, float* __restrict__ counts) {
    int n = blockIdx.x * 256 + threadIdx.x;
    unsafeAtomicAdd(&counts[(int)idxf[n]], 1.0f);
}

// ---------------- quantize + zq + loss --------------------------------------
__global__ __launch_bounds__(256) void quant_kernel(
    const float* __restrict__ z, const float* __restrict__ E,
    const float* __restrict__ idxf, float* __restrict__ zq,
    float* __restrict__ lossacc) {
    const int b  = blockIdx.x >> 4;
    const int d0 = (blockIdx.x & 15) * 16;
    const int tid = threadIdx.x;
    const int hw = tid * 4;
    const float* zb = z  + (size_t)b * (D_ * HW_);
    float*       qb = zq + (size_t)b * (D_ * HW_);

    int idx[4];
    #pragma unroll
    for (int i = 0; i < 4; ++i) idx[i] = (int)idxf[b * HW_ + hw + i];

    float loss = 0.f;
    for (int db = 0; db < 4; ++db) {
        int d = d0 + db * 4;
        float qa[4][4];
        #pragma unroll
        for (int i = 0; i < 4; ++i)
            *(float4*)&qa[i][0] = *(const float4*)&E[(size_t)idx[i] * D_ + d];
        #pragma unroll
        for (int dd = 0; dd < 4; ++dd) {
            float4 z4 = *(const float4*)&zb[(size_t)(d + dd) * HW_ + hw];
            float zv[4] = {z4.x, z4.y, z4.z, z4.w};
            float o[4];
            #pragma unroll
            for (int i = 0; i < 4; ++i) {
                float diff = __fsub_rn(qa[i][dd], zv[i]);
                float zqv  = __fadd_rn(zv[i], diff);
                o[i] = zqv;
                float l = __fsub_rn(zqv, zv[i]);
                loss = __builtin_fmaf(l, l, loss);
            }
            *(float4*)&qb[(size_t)(d + dd) * HW_ + hw] = make_float4(o[0], o[1], o[2], o[3]);
        }
    }
    __shared__ float ls[256];
    ls[tid] = loss;
    __syncthreads();
    for (int s = 128; s > 0; s >>= 1) {
        if (tid < s) ls[tid] += ls[tid + s];
        __syncthreads();
    }
    if (tid == 0) unsafeAtomicAdd(lossacc, ls[0]);
}

// ---------------- per-code scalars ------------------------------------------
__global__ __launch_bounds__(1024) void fin1(
    const float* __restrict__ counts, const float* __restrict__ cs_in,
    float* __restrict__ out, float* __restrict__ smoothed) {
    const int k = threadIdx.x;
    __shared__ float red[1024];
    float c = counts[k];
    float csn = __fadd_rn(__fmul_rn(DECAY_F, cs_in[k]), __fmul_rn(W_NEW, c));
    out[OFF_CSN + k]  = csn;
    out[OFF_USED + k] = (c > 0.f) ? 1.f : 0.f;
    red[k] = csn; __syncthreads();
    for (int s = 512; s > 0; s >>= 1) { if (k < s) red[k] += red[k + s]; __syncthreads(); }
    float n_ = red[0]; __syncthreads();
    red[k] = c; __syncthreads();
    for (int s = 512; s > 0; s >>= 1) { if (k < s) red[k] += red[k + s]; __syncthreads(); }
    float total = red[0]; __syncthreads();
    float p = c / total;
    red[k] = p * logf(p + 1e-10f); __syncthreads();
    for (int s = 512; s > 0; s >>= 1) { if (k < s) red[k] += red[k + s]; __syncthreads(); }
    if (k == 0) out[OFF_PERP] = expf(-red[0]);
    smoothed[k] = __fmul_rn(__fdiv_rn(__fadd_rn(csn, EPS_F), __fadd_rn(n_, KEPS_F)), n_);
}

__global__ void fin_loss(const float* __restrict__ lossacc, float* __restrict__ out) {
    if (threadIdx.x == 0) out[OFF_LOSS] = lossacc[0] / 16777216.0f;
}

// ---------------- scan / scatter --------------------------------------------
__global__ __launch_bounds__(1024) void scan_kernel(
    const float* __restrict__ counts, int* __restrict__ offs,
    int* __restrict__ cursor) {
    __shared__ int s[1024];
    const int k = threadIdx.x;
    int c = (int)counts[k];
    s[k] = c; __syncthreads();
    for (int dlt = 1; dlt < 1024; dlt <<= 1) {
        int v = (k >= dlt) ? s[k - dlt] : 0;
        __syncthreads();
        s[k] += v;
        __syncthreads();
    }
    int off = s[k] - c;
    offs[k] = off;
    cursor[k] = off;
}

__global__ __launch_bounds__(256) void scatter_kernel(
    const float* __restrict__ idxf, int* __restrict__ cursor,
    int* __restrict__ bucket) {
    int n = blockIdx.x * 256 + threadIdx.x;
    int k = (int)idxf[n];
    int pos = atomicAdd(&cursor[k], 1);
    bucket[pos] = n;
}

// ---------------- per-code gather-sum (coalesced via bf16 planes) -----------
__global__ __launch_bounds__(256) void code_update(
    const unsigned short* __restrict__ zhi, const unsigned short* __restrict__ zlo,
    const float* __restrict__ eavg_in, const float* __restrict__ smoothed,
    const float* __restrict__ counts, const int* __restrict__ offs,
    const int* __restrict__ bucket, float* __restrict__ out) {
    const int k = blockIdx.x;
    const int d = threadIdx.x;
    const int off = offs[k];
    const int cnt = (int)counts[k];
    float acc = 0.f;
    for (int i = 0; i < cnt; ++i) {
        int p = bucket[off + i];
        size_t base = (size_t)p * D_ + d;
        acc += bf2f(zhi[base]) + bf2f(zlo[base]);
    }
    int e = k * D_ + d;
    float ean = __fadd_rn(__fmul_rn(DECAY_F, eavg_in[e]), __fmul_rn(W_NEW, acc));
    out[OFF_EAVG + e] = ean;
    out[OFF_ENEW + e] = __fdiv_rn(ean, smoothed[k]);
}

extern "C" void kernel_launch(void* const* d_in, const int* in_sizes, int n_in,
                              void* d_out, int out_size, void* d_ws, size_t ws_size,
                              hipStream_t stream) {
    const float* z    = (const float*)d_in[0];
    const float* E    = (const float*)d_in[1];
    const float* cs   = (const float*)d_in[2];
    const float* eavg = (const float*)d_in[3];
    float* out = (float*)d_out;
    float* wsf = (float*)d_ws;
    int*   wsi = (int*)d_ws;

    unsigned short* zhiP = (unsigned short*)(out + OFF_ZQ);
    unsigned short* zloP = zhiP + (size_t)N_ * D_;
    unsigned short* ehiP = (unsigned short*)(out + OFF_ENEW);
    unsigned short* eloP = ehiP + (size_t)K_ * D_;

    hipMemsetAsync(d_ws, 0, 32768, stream);  // counts, loss, flagcnt

    prep_z<<<1024, 256, 0, stream>>>(z, zhiP, zloP, wsf + WS_Z2);
    prep_e<<<K_, 64, 0, stream>>>(E, ehiP, eloP, wsf + WS_E2);
    argmin_mfma<<<N_ / 64, 256, 0, stream>>>(zhiP, zloP, ehiP, eloP,
                                             wsf + WS_E2, out + OFF_IDX,
                                             wsi + WS_FLAG, wsi + WS_FLAGCNT);
    rescue_kernel<<<256, 256, 0, stream>>>(z, E, wsf + WS_E2, wsf + WS_Z2,
                                           wsi + WS_FLAG, wsi + WS_FLAGCNT,
                                           out + OFF_IDX);
    count_kernel<<<N_ / 256, 256, 0, stream>>>(out + OFF_IDX, wsf + WS_CNT);
    fin1<<<1, 1024, 0, stream>>>(wsf + WS_CNT, cs, out, wsf + WS_SMOO);
    scan_kernel<<<1, 1024, 0, stream>>>(wsf + WS_CNT, wsi + WS_OFFS, wsi + WS_CURS);
    scatter_kernel<<<N_ / 256, 256, 0, stream>>>(out + OFF_IDX, wsi + WS_CURS,
                                                 wsi + WS_BUCKET);
    // code_update MUST precede quant_kernel: it reads the bf16 z-planes that
    // live in the OFF_ZQ output region, which quant_kernel overwrites.
    code_update<<<K_, 256, 0, stream>>>(zhiP, zloP, eavg, wsf + WS_SMOO,
                                        wsf + WS_CNT, wsi + WS_OFFS,
                                        wsi + WS_BUCKET, out);
    quant_kernel<<<B_ * 16, 256, 0, stream>>>(z, E, out + OFF_IDX, out + OFF_ZQ,
                                              wsf + WS_LOSS);
    fin_loss<<<1, 64, 0, stream>>>(wsf + WS_LOSS, out);
}

// Round 8
// 647.339 us; speedup vs baseline: 1.5035x; 1.1092x over previous
//
#include <hip/hip_runtime.h>
#include <hip/hip_bf16.h>

#define D_   256
#define K_   1024
#define HW_  1024
#define B_   64
#define N_   65536

#define OFF_ZQ   ((size_t)0)
#define OFF_LOSS ((size_t)16777216)
#define OFF_IDX  ((size_t)16777217)
#define OFF_PERP ((size_t)16842753)
#define OFF_USED ((size_t)16842754)
#define OFF_ENEW ((size_t)16843778)
#define OFF_CSN  ((size_t)17105922)
#define OFF_EAVG ((size_t)17106946)

#define DECAY_F 0.99f
#define W_NEW   ((float)(1.0 - 0.99))
#define EPS_F   1e-5f
#define KEPS_F  ((float)(1024.0 * 1e-5))
#define MARGIN  0.00390625f

// ws layout (float offsets)
#define WS_E2      0        // 1024
#define WS_CNT     1024     // 1024
#define WS_LOSS    2048     // 1
#define WS_FLAGCNT 2052     // 1 (int)
#define WS_SMOO    2304     // 1024
#define WS_OFFS    3328     // 1024 (int)
#define WS_CURS    4352     // 1024 (int)
#define WS_Z2      8192     // 65536
#define WS_BUCKET  73728    // 65536 (int)
#define WS_FLAG    139264   // 65536 (int)

typedef __attribute__((ext_vector_type(8))) short bf16x8;
typedef __attribute__((ext_vector_type(8))) unsigned short u16x8;
typedef __attribute__((ext_vector_type(4))) float f32x4;

static __device__ __forceinline__ float bf2f(unsigned short u) {
    return __uint_as_float(((unsigned int)u) << 16);
}
static __device__ __forceinline__ unsigned short f2bf(float x) {
    unsigned int u = __float_as_uint(x);
    return (unsigned short)((u + 0x7fffu + ((u >> 16) & 1u)) >> 16);
}

// ---------------- prep_z: z[b][d][hw] f32 -> zhiT/zloT [pt][d] bf16 + z2 ----
__global__ __launch_bounds__(256) void prep_z(
    const float* __restrict__ z, unsigned short* __restrict__ zhi,
    unsigned short* __restrict__ zlo, float* __restrict__ z2g) {
    __shared__ float tile[128][68];
    __shared__ double zred[64][4];
    const int tid = threadIdx.x;
    const int b   = blockIdx.x >> 4;
    const int hw0 = (blockIdx.x & 15) * 64;
    const float* zb = z + (size_t)b * (D_ * HW_);

    const int hw = tid >> 2, dq = tid & 3;
    double zacc = 0.0;

    for (int h = 0; h < 2; ++h) {
        #pragma unroll
        for (int ch = 0; ch < 8; ++ch) {
            int d = h * 128 + ch * 16 + (tid >> 4);
            int c4 = (tid & 15) * 4;
            float4 v = *(const float4*)&zb[(size_t)d * HW_ + hw0 + c4];
            tile[ch * 16 + (tid >> 4)][c4 + 0] = v.x;
            tile[ch * 16 + (tid >> 4)][c4 + 1] = v.y;
            tile[ch * 16 + (tid >> 4)][c4 + 2] = v.z;
            tile[ch * 16 + (tid >> 4)][c4 + 3] = v.w;
        }
        __syncthreads();
        size_t pt = (size_t)b * HW_ + hw0 + hw;
        #pragma unroll
        for (int jb = 0; jb < 4; ++jb) {
            unsigned short hs[8], ls[8];
            #pragma unroll
            for (int e = 0; e < 8; ++e) {
                float v = tile[dq * 32 + jb * 8 + e][hw];
                zacc += (double)v * (double)v;
                unsigned short hh = f2bf(v);
                hs[e] = hh;
                ls[e] = f2bf(v - bf2f(hh));
            }
            size_t dst = pt * D_ + h * 128 + dq * 32 + jb * 8;
            *(u16x8*)&zhi[dst] = *(u16x8*)hs;
            *(u16x8*)&zlo[dst] = *(u16x8*)ls;
        }
        __syncthreads();
    }
    zred[hw][dq] = zacc;
    __syncthreads();
    if (tid < 64) {
        double s = zred[tid][0] + zred[tid][1] + zred[tid][2] + zred[tid][3];
        z2g[b * HW_ + hw0 + tid] = (float)s;
    }
}

// ---------------- prep_e: E[k][d] f32 -> ehi/elo bf16 + e2 (f64) ------------
__global__ __launch_bounds__(64) void prep_e(
    const float* __restrict__ E, unsigned short* __restrict__ ehi,
    unsigned short* __restrict__ elo, float* __restrict__ e2g) {
    int k = blockIdx.x;
    int lane = threadIdx.x;
    float4 v = *(const float4*)&E[(size_t)k * D_ + lane * 4];
    double s = (double)v.x * v.x + (double)v.y * v.y +
               (double)v.z * v.z + (double)v.w * v.w;
    float vv[4] = {v.x, v.y, v.z, v.w};
    ushort4 hs, ls;
    unsigned short* hp = (unsigned short*)&hs;
    unsigned short* lp = (unsigned short*)&ls;
    #pragma unroll
    for (int e = 0; e < 4; ++e) {
        unsigned short hh = f2bf(vv[e]);
        hp[e] = hh;
        lp[e] = f2bf(vv[e] - bf2f(hh));
    }
    *(ushort4*)&ehi[(size_t)k * D_ + lane * 4] = hs;
    *(ushort4*)&elo[(size_t)k * D_ + lane * 4] = ls;
    #pragma unroll
    for (int m = 32; m > 0; m >>= 1) s += __shfl_xor(s, m, 64);
    if (lane == 0) e2g[k] = (float)s;
}

// ---------------- argmin via bf16x3 MFMA: 64 pts/block, 256 thr -------------
// Wave (wr,wq): pt-half wr (32 pts), code-half wq (512 codes, kt=8 x 64).
// Per-thread state halved vs r7 (acc 32 + frags 48 + min 24): no spill,
// LDS 64 KB -> 2 blocks/CU -> 8 waves/CU.
__global__ __launch_bounds__(256) void argmin_mfma(
    const unsigned short* __restrict__ zhi, const unsigned short* __restrict__ zlo,
    const unsigned short* __restrict__ ehi, const unsigned short* __restrict__ elo,
    const float* __restrict__ e2g, float* __restrict__ out_idx,
    int* __restrict__ flagged, int* __restrict__ flagcnt) {
    __shared__ unsigned short zl[2][64][256];              // 64 KB exactly
    float (*mred)[64][3] = (float(*)[64][3])&zl[0][0][0];  // aliased post-loop

    const int tid  = threadIdx.x;
    const int lane = tid & 63;
    const int wid  = tid >> 6;
    const int wr = wid & 1;        // pt-half
    const int wq = wid >> 1;       // code-half
    const int x = lane & 15, g = lane >> 4;
    const int pt0 = blockIdx.x * 64;

    // ---- stage both z planes once (coalesced 16B chunks, swizzled dest)
    {
        const unsigned short* s0 = zhi + (size_t)pt0 * D_;
        const unsigned short* s1 = zlo + (size_t)pt0 * D_;
        #pragma unroll
        for (int i = 0; i < 8; ++i) {
            int c = i * 256 + tid;             // 16B chunk id, 0..2047
            int pt = c >> 5, d16 = c & 31;
            int soff = (d16 * 8) ^ ((pt & 7) << 3);
            *(u16x8*)&zl[0][pt][soff] = *(const u16x8*)&s0[c * 8];
            *(u16x8*)&zl[1][pt][soff] = *(const u16x8*)&s1[c * 8];
        }
    }
    __syncthreads();

    float m1[8], m2[8];
    int   a1[8];
    #pragma unroll
    for (int s = 0; s < 8; ++s) { m1[s] = 3.4e38f; m2[s] = 3.4e38f; a1[s] = 0; }

    for (int kt = 0; kt < 8; ++kt) {
        const int kcode0 = wq * 512 + kt * 64;
        f32x4 acc[2][4];
        #pragma unroll
        for (int mf = 0; mf < 2; ++mf)
            #pragma unroll
            for (int nf = 0; nf < 4; ++nf) acc[mf][nf] = (f32x4)0.f;

        for (int dc = 0; dc < 8; ++dc) {
            bf16x8 bh[4], bl[4];
            #pragma unroll
            for (int nf = 0; nf < 4; ++nf) {
                size_t base = (size_t)(kcode0 + nf * 16 + x) * D_ + dc * 32 + g * 8;
                bh[nf] = *(const bf16x8*)&ehi[base];
                bl[nf] = *(const bf16x8*)&elo[base];
            }
            bf16x8 ah[2], al[2];
            #pragma unroll
            for (int mf = 0; mf < 2; ++mf) {
                int pt = wr * 32 + mf * 16 + x;
                int soff = (dc * 32 + g * 8) ^ ((pt & 7) << 3);
                ah[mf] = *(const bf16x8*)&zl[0][pt][soff];
                al[mf] = *(const bf16x8*)&zl[1][pt][soff];
            }
            #pragma unroll
            for (int mf = 0; mf < 2; ++mf)
                #pragma unroll
                for (int nf = 0; nf < 4; ++nf) {
                    acc[mf][nf] = __builtin_amdgcn_mfma_f32_16x16x32_bf16(ah[mf], bh[nf], acc[mf][nf], 0, 0, 0);
                    acc[mf][nf] = __builtin_amdgcn_mfma_f32_16x16x32_bf16(ah[mf], bl[nf], acc[mf][nf], 0, 0, 0);
                    acc[mf][nf] = __builtin_amdgcn_mfma_f32_16x16x32_bf16(al[mf], bh[nf], acc[mf][nf], 0, 0, 0);
                }
        }

        // epilogue: dist = e2 - 2S ; running (m1, a1, m2) per owned pt-slot
        float e2v[4];
        int   cbase[4];
        #pragma unroll
        for (int nf = 0; nf < 4; ++nf) {
            cbase[nf] = kcode0 + nf * 16 + x;
            e2v[nf] = e2g[cbase[nf]];
        }
        #pragma unroll
        for (int mf = 0; mf < 2; ++mf)
            #pragma unroll
            for (int reg = 0; reg < 4; ++reg) {
                int s = mf * 4 + reg;
                #pragma unroll
                for (int nf = 0; nf < 4; ++nf) {
                    float dist = __builtin_fmaf(-2.0f, acc[mf][nf][reg], e2v[nf]);
                    if (dist < m1[s]) { m2[s] = m1[s]; m1[s] = dist; a1[s] = cbase[nf]; }
                    else m2[s] = fminf(m2[s], dist);
                }
            }
    }

    // butterfly across the 16 col-lanes (x) sharing each pt (register-only)
    #pragma unroll
    for (int mask = 1; mask < 16; mask <<= 1) {
        #pragma unroll
        for (int s = 0; s < 8; ++s) {
            float om1 = __shfl_xor(m1[s], mask, 64);
            int   oa  = __shfl_xor(a1[s], mask, 64);
            float om2 = __shfl_xor(m2[s], mask, 64);
            bool take = (om1 < m1[s]) || (om1 == m1[s] && oa < a1[s]);
            float loser = take ? m1[s] : om1;
            m2[s] = fminf(fminf(m2[s], om2), loser);
            if (take) { m1[s] = om1; a1[s] = oa; }
        }
    }
    __syncthreads();   // all waves done reading zl before aliasing as mred
    if (x < 2) {
        // lane x writes the mf=x slots; pt = wr*32 + x*16 + g*4 + reg
        #pragma unroll
        for (int reg = 0; reg < 4; ++reg) {
            int s = x * 4 + reg;
            int ptl = wr * 32 + x * 16 + g * 4 + reg;
            mred[wq][ptl][0] = m1[s];
            mred[wq][ptl][1] = (float)a1[s];
            mred[wq][ptl][2] = m2[s];
        }
    }
    __syncthreads();
    if (tid < 64) {
        float m1f = mred[0][tid][0], m2f = mred[0][tid][2];
        int   a1f = (int)mred[0][tid][1];
        {
            float om1 = mred[1][tid][0], om2 = mred[1][tid][2];
            int   oa  = (int)mred[1][tid][1];
            bool take = (om1 < m1f) || (om1 == m1f && oa < a1f);
            float loser = take ? m1f : om1;
            m2f = fminf(fminf(m2f, om2), loser);
            if (take) { m1f = om1; a1f = oa; }
        }
        out_idx[pt0 + tid] = (float)a1f;
        if (m2f - m1f < MARGIN) {
            int pos = atomicAdd(flagcnt, 1);
            flagged[pos] = pt0 + tid;
        }
    }
}

// ---------------- rescue: exact f32 re-argmin for flagged points ------------
__global__ __launch_bounds__(256) void rescue_kernel(
    const float* __restrict__ z, const float* __restrict__ E,
    const float* __restrict__ e2g, const float* __restrict__ z2g,
    const int* __restrict__ flagged, const int* __restrict__ flagcnt,
    float* __restrict__ out_idx) {
    __shared__ float zs[8][257];
    __shared__ float zz[8];
    __shared__ float redm[256];
    __shared__ int   reda[256];
    const int tid = threadIdx.x;
    const int nflag = flagcnt[0];
    const int nb = (nflag + 7) >> 3;

    for (int bi = blockIdx.x; bi < nb; bi += gridDim.x) {
        int base = bi * 8;
        int cnt = nflag - base; if (cnt > 8) cnt = 8;
        for (int j = 0; j < cnt; ++j) {
            int p = flagged[base + j];
            zs[j][tid] = z[(size_t)(p >> 10) * (D_ * HW_) + (size_t)tid * HW_ + (p & 1023)];
        }
        if (tid < cnt) zz[tid] = z2g[flagged[base + tid]];
        __syncthreads();

        float mj[8], distc[8];
        int   aj[8];
        #pragma unroll
        for (int j = 0; j < 8; ++j) { mj[j] = 3.4e38f; aj[j] = 0; }

        for (int c = 0; c < 4; ++c) {
            int code = tid * 4 + c;
            const float* er = E + (size_t)code * D_;
            float accj[8];
            #pragma unroll
            for (int j = 0; j < 8; ++j) accj[j] = 0.f;
            for (int d = 0; d < D_; ++d) {
                float ev = er[d];
                #pragma unroll
                for (int j = 0; j < 8; ++j)
                    accj[j] = __builtin_fmaf(ev, zs[j][d], accj[j]);
            }
            float e2c = e2g[code];
            #pragma unroll
            for (int j = 0; j < 8; ++j) {
                distc[j] = __fsub_rn(__fadd_rn(zz[j], e2c), __fmul_rn(2.0f, accj[j]));
                if (distc[j] < mj[j]) { mj[j] = distc[j]; aj[j] = code; }
            }
        }
        for (int j = 0; j < cnt; ++j) {
            redm[tid] = mj[j]; reda[tid] = aj[j];
            __syncthreads();
            for (int s = 128; s > 0; s >>= 1) {
                if (tid < s) {
                    float om = redm[tid + s]; int oa = reda[tid + s];
                    if (om < redm[tid] || (om == redm[tid] && oa < reda[tid])) {
                        redm[tid] = om; reda[tid] = oa;
                    }
                }
                __syncthreads();
            }
            if (tid == 0) out_idx[flagged[base + j]] = (float)reda[0];
            __syncthreads();
        }
        __syncthreads();
    }
}

// ---------------- counts from final indices ---------------------------------
__global__ __launch_bounds__(256) void count_kernel(
    const float* __restrict__ idxf, float* __restrict__ counts) {
    int n = blockIdx.x * 256 + threadIdx.x;
    unsafeAtomicAdd(&counts[(int)idxf[n]], 1.0f);
}

// ---------------- quantize + zq + loss --------------------------------------
__global__ __launch_bounds__(256) void quant_kernel(
    const float* __restrict__ z, const float* __restrict__ E,
    const float* __restrict__ idxf, float* __restrict__ zq,
    float* __restrict__ lossacc) {
    const int b  = blockIdx.x >> 4;
    const int d0 = (blockIdx.x & 15) * 16;
    const int tid = threadIdx.x;
    const int hw = tid * 4;
    const float* zb = z  + (size_t)b * (D_ * HW_);
    float*       qb = zq + (size_t)b * (D_ * HW_);

    int idx[4];
    #pragma unroll
    for (int i = 0; i < 4; ++i) idx[i] = (int)idxf[b * HW_ + hw + i];

    float loss = 0.f;
    for (int db = 0; db < 4; ++db) {
        int d = d0 + db * 4;
        float qa[4][4];
        #pragma unroll
        for (int i = 0; i < 4; ++i)
            *(float4*)&qa[i][0] = *(const float4*)&E[(size_t)idx[i] * D_ + d];
        #pragma unroll
        for (int dd = 0; dd < 4; ++dd) {
            float4 z4 = *(const float4*)&zb[(size_t)(d + dd) * HW_ + hw];
            float zv[4] = {z4.x, z4.y, z4.z, z4.w};
            float o[4];
            #pragma unroll
            for (int i = 0; i < 4; ++i) {
                float diff = __fsub_rn(qa[i][dd], zv[i]);
                float zqv  = __fadd_rn(zv[i], diff);
                o[i] = zqv;
                float l = __fsub_rn(zqv, zv[i]);
                loss = __builtin_fmaf(l, l, loss);
            }
            *(float4*)&qb[(size_t)(d + dd) * HW_ + hw] = make_float4(o[0], o[1], o[2], o[3]);
        }
    }
    __shared__ float ls[256];
    ls[tid] = loss;
    __syncthreads();
    for (int s = 128; s > 0; s >>= 1) {
        if (tid < s) ls[tid] += ls[tid + s];
        __syncthreads();
    }
    if (tid == 0) unsafeAtomicAdd(lossacc, ls[0]);
}

// ---------------- per-code scalars ------------------------------------------
__global__ __launch_bounds__(1024) void fin1(
    const float* __restrict__ counts, const float* __restrict__ cs_in,
    float* __restrict__ out, float* __restrict__ smoothed) {
    const int k = threadIdx.x;
    __shared__ float red[1024];
    float c = counts[k];
    float csn = __fadd_rn(__fmul_rn(DECAY_F, cs_in[k]), __fmul_rn(W_NEW, c));
    out[OFF_CSN + k]  = csn;
    out[OFF_USED + k] = (c > 0.f) ? 1.f : 0.f;
    red[k] = csn; __syncthreads();
    for (int s = 512; s > 0; s >>= 1) { if (k < s) red[k] += red[k + s]; __syncthreads(); }
    float n_ = red[0]; __syncthreads();
    red[k] = c; __syncthreads();
    for (int s = 512; s > 0; s >>= 1) { if (k < s) red[k] += red[k + s]; __syncthreads(); }
    float total = red[0]; __syncthreads();
    float p = c / total;
    red[k] = p * logf(p + 1e-10f); __syncthreads();
    for (int s = 512; s > 0; s >>= 1) { if (k < s) red[k] += red[k + s]; __syncthreads(); }
    if (k == 0) out[OFF_PERP] = expf(-red[0]);
    smoothed[k] = __fmul_rn(__fdiv_rn(__fadd_rn(csn, EPS_F), __fadd_rn(n_, KEPS_F)), n_);
}

__global__ void fin_loss(const float* __restrict__ lossacc, float* __restrict__ out) {
    if (threadIdx.x == 0) out[OFF_LOSS] = lossacc[0] / 16777216.0f;
}

// ---------------- scan / scatter --------------------------------------------
__global__ __launch_bounds__(1024) void scan_kernel(
    const float* __restrict__ counts, int* __restrict__ offs,
    int* __restrict__ cursor) {
    __shared__ int s[1024];
    const int k = threadIdx.x;
    int c = (int)counts[k];
    s[k] = c; __syncthreads();
    for (int dlt = 1; dlt < 1024; dlt <<= 1) {
        int v = (k >= dlt) ? s[k - dlt] : 0;
        __syncthreads();
        s[k] += v;
        __syncthreads();
    }
    int off = s[k] - c;
    offs[k] = off;
    cursor[k] = off;
}

__global__ __launch_bounds__(256) void scatter_kernel(
    const float* __restrict__ idxf, int* __restrict__ cursor,
    int* __restrict__ bucket) {
    int n = blockIdx.x * 256 + threadIdx.x;
    int k = (int)idxf[n];
    int pos = atomicAdd(&cursor[k], 1);
    bucket[pos] = n;
}

// ---------------- per-code gather-sum (coalesced via bf16 planes) -----------
__global__ __launch_bounds__(256) void code_update(
    const unsigned short* __restrict__ zhi, const unsigned short* __restrict__ zlo,
    const float* __restrict__ eavg_in, const float* __restrict__ smoothed,
    const float* __restrict__ counts, const int* __restrict__ offs,
    const int* __restrict__ bucket, float* __restrict__ out) {
    const int k = blockIdx.x;
    const int d = threadIdx.x;
    const int off = offs[k];
    const int cnt = (int)counts[k];
    float acc = 0.f;
    for (int i = 0; i < cnt; ++i) {
        int p = bucket[off + i];
        size_t base = (size_t)p * D_ + d;
        acc += bf2f(zhi[base]) + bf2f(zlo[base]);
    }
    int e = k * D_ + d;
    float ean = __fadd_rn(__fmul_rn(DECAY_F, eavg_in[e]), __fmul_rn(W_NEW, acc));
    out[OFF_EAVG + e] = ean;
    out[OFF_ENEW + e] = __fdiv_rn(ean, smoothed[k]);
}

extern "C" void kernel_launch(void* const* d_in, const int* in_sizes, int n_in,
                              void* d_out, int out_size, void* d_ws, size_t ws_size,
                              hipStream_t stream) {
    const float* z    = (const float*)d_in[0];
    const float* E    = (const float*)d_in[1];
    const float* cs   = (const float*)d_in[2];
    const float* eavg = (const float*)d_in[3];
    float* out = (float*)d_out;
    float* wsf = (float*)d_ws;
    int*   wsi = (int*)d_ws;

    unsigned short* zhiP = (unsigned short*)(out + OFF_ZQ);
    unsigned short* zloP = zhiP + (size_t)N_ * D_;
    unsigned short* ehiP = (unsigned short*)(out + OFF_ENEW);
    unsigned short* eloP = ehiP + (size_t)K_ * D_;

    hipMemsetAsync(d_ws, 0, 32768, stream);  // counts, loss, flagcnt

    prep_z<<<1024, 256, 0, stream>>>(z, zhiP, zloP, wsf + WS_Z2);
    prep_e<<<K_, 64, 0, stream>>>(E, ehiP, eloP, wsf + WS_E2);
    argmin_mfma<<<N_ / 64, 256, 0, stream>>>(zhiP, zloP, ehiP, eloP,
                                             wsf + WS_E2, out + OFF_IDX,
                                             wsi + WS_FLAG, wsi + WS_FLAGCNT);
    rescue_kernel<<<256, 256, 0, stream>>>(z, E, wsf + WS_E2, wsf + WS_Z2,
                                           wsi + WS_FLAG, wsi + WS_FLAGCNT,
                                           out + OFF_IDX);
    count_kernel<<<N_ / 256, 256, 0, stream>>>(out + OFF_IDX, wsf + WS_CNT);
    fin1<<<1, 1024, 0, stream>>>(wsf + WS_CNT, cs, out, wsf + WS_SMOO);
    scan_kernel<<<1, 1024, 0, stream>>>(wsf + WS_CNT, wsi + WS_OFFS, wsi + WS_CURS);
    scatter_kernel<<<N_ / 256, 256, 0, stream>>>(out + OFF_IDX, wsi + WS_CURS,
                                                 wsi + WS_BUCKET);
    // code_update MUST precede quant_kernel: it reads the bf16 z-planes that
    // live in the OFF_ZQ output region, which quant_kernel overwrites.
    code_update<<<K_, 256, 0, stream>>>(zhiP, zloP, eavg, wsf + WS_SMOO,
                                        wsf + WS_CNT, wsi + WS_OFFS,
                                        wsi + WS_BUCKET, out);
    quant_kernel<<<B_ * 16, 256, 0, stream>>>(z, E, out + OFF_IDX, out + OFF_ZQ,
                                              wsf + WS_LOSS);
    fin_loss<<<1, 64, 0, stream>>>(wsf + WS_LOSS, out);
}